// Round 10
// baseline (806.901 us; speedup 1.0000x reference)
//
#include <hip/hip_runtime.h>

// DKVMN forward, v10 — fuse the MLP tail into the state kernel.
//  R9 post-mortem: state is issue-bound (265us VALU issue of 356us; pk==scalar).
//  Residual target is the ~145us of small kernels + gaps. Key insight: block b's
//  MLP depends ONLY on RD rows block b wrote -> per-block tail fusion, no
//  inter-block sync. RD rows are L2-hot at tail time (160KB/block).
//  k1 build_wq : W[5001,50]=softmax(q_emb@K^T), Q1[5001,50]=q_emb@W1[200:250]+b1
//  k2 build_ea : EA[10001,200] packed bf16 {e,a} (f32 math, proven)
//  k2b pack_w1 : W1 -> bf16 MFMA B-frag order (now 56 blocks, was 1)
//  k3 dkvmn_state: barrier-free recurrence (256 thr, scalar fmaf, SGPR wrow,
//      EA depth-2) + fused MFMA MLP tail per block (1 barrier total).
// Workspace: Wt 1MB | Q1 1MB | EA 8MB | W1s 32KB | RD 164MB (~174MB total).

#define NQ1   5001
#define NQA   10001
#define MEMN  50
#define KD    50
#define VD    200
#define FC    50
#define BB    2048
#define SS    200
#define EA_R  16

typedef unsigned int   u32;
typedef unsigned short u16;
typedef short  s8v  __attribute__((ext_vector_type(8)));   // 8 bf16 (4 VGPRs)
typedef float  f4v  __attribute__((ext_vector_type(4)));   // MFMA C/D

__device__ __forceinline__ float fast_sigmoid(float x) { return 1.f / (1.f + __expf(-x)); }
__device__ __forceinline__ float fast_tanh(float x) {
    float e2 = __expf(2.f * x);           // inf-safe
    return 1.f - 2.f / (e2 + 1.f);
}
__device__ __forceinline__ float bfu16_to_f(u16 u) {
    union { float f; u32 i; } x; x.i = ((u32)u) << 16; return x.f;
}
__device__ __forceinline__ u16 f_to_bfu16(float f) {   // RNE, finite inputs
    union { float f; u32 i; } x; x.f = f;
    return (u16)((x.i + 0x7fffu + ((x.i >> 16) & 1u)) >> 16);
}

// ---- per-q tables ----
__global__ void build_wq(const float* __restrict__ qemb,
                         const float* __restrict__ km,
                         const float* __restrict__ w1,
                         const float* __restrict__ b1,
                         float* __restrict__ Wt, float* __restrict__ Q1) {
    const int q = blockIdx.x;
    const int f = threadIdx.x;          // one wave
    __shared__ float qrow[KD];
    if (f < KD) qrow[f] = qemb[q * KD + f];
    __syncthreads();

    float s = -1e30f;
    if (f < MEMN) {
        s = 0.f;
        #pragma unroll
        for (int k = 0; k < KD; ++k) s = fmaf(qrow[k], km[f * KD + k], s);
    }
    float mx = s;
    #pragma unroll
    for (int off = 32; off >= 1; off >>= 1) mx = fmaxf(mx, __shfl_xor(mx, off, 64));
    float e = (f < MEMN) ? __expf(s - mx) : 0.f;
    float sum = e;
    #pragma unroll
    for (int off = 32; off >= 1; off >>= 1) sum += __shfl_xor(sum, off, 64);
    if (f < MEMN) Wt[q * MEMN + f] = e / sum;

    if (f < FC) {
        float h = b1[f];
        #pragma unroll
        for (int k = 0; k < KD; ++k)
            h = fmaf(qrow[k], w1[(VD + k) * FC + f], h);
        Q1[q * FC + f] = h;
    }
}

// ---- per-qa table, packed {e,a} bf16 (f32 math — protocol-proven) ----
__global__ void build_ea(const float* __restrict__ qaemb,
                         const float* __restrict__ ew,
                         const float* __restrict__ ebias,
                         const float* __restrict__ aw,
                         const float* __restrict__ abias,
                         u32* __restrict__ EA) {
    __shared__ float qT[VD][EA_R];
    const int tid = threadIdx.x;
    const int r0 = blockIdx.x * EA_R;
    if (tid < VD) {
        #pragma unroll
        for (int r = 0; r < EA_R; ++r) {
            int row = r0 + r;
            qT[tid][r] = (row < NQA) ? qaemb[(size_t)row * VD + tid] : 0.f;
        }
    }
    __syncthreads();
    if (tid >= VD) return;

    float accE[EA_R], accA[EA_R];
    #pragma unroll
    for (int r = 0; r < EA_R; ++r) { accE[r] = 0.f; accA[r] = 0.f; }
    for (int k = 0; k < VD; ++k) {
        float we = ew[k * VD + tid];
        float wa = aw[k * VD + tid];
        #pragma unroll
        for (int r = 0; r < EA_R; ++r) {
            float qv = qT[k][r];
            accE[r] = fmaf(qv, we, accE[r]);
            accA[r] = fmaf(qv, wa, accA[r]);
        }
    }
    float be = ebias[tid], ba = abias[tid];
    #pragma unroll
    for (int r = 0; r < EA_R; ++r) {
        int row = r0 + r;
        if (row < NQA) {
            u16 e16 = f_to_bfu16(fast_sigmoid(accE[r] + be));
            u16 a16 = f_to_bfu16(fast_tanh(accA[r] + ba));
            EA[(size_t)row * VD + tid] = (u32)e16 | ((u32)a16 << 16);
        }
    }
}

// ---- W1 -> bf16 MFMA B-fragment order: idx = ((nt*7+kt)*64+lane)*8+j,
//      element = w1[k = kt*32+(lane>>4)*8+j][n = nt*16+(lane&15)], 0-padded ----
__global__ void pack_w1(const float* __restrict__ w1, u16* __restrict__ W1s) {
    for (int idx = blockIdx.x * blockDim.x + threadIdx.x; idx < 4 * 7 * 64 * 8;
         idx += gridDim.x * blockDim.x) {
        int j    = idx & 7;
        int lane = (idx >> 3) & 63;
        int kt   = (idx >> 9) % 7;
        int nt   = idx / 3584;
        int k = kt * 32 + ((lane >> 4) << 3) + j;
        int n = nt * 16 + (lane & 15);
        float v = (k < VD && n < FC) ? w1[k * FC + n] : 0.f;
        W1s[idx] = f_to_bfu16(v);
    }
}

// ---- recurrence + fused MLP tail ----
__global__ __launch_bounds__(256) void dkvmn_state(
        const int* __restrict__ qd, const int* __restrict__ qad,
        const float* __restrict__ Wtab, const u32* __restrict__ EA,
        const float* __restrict__ ivm, u16* __restrict__ READ,
        const float* __restrict__ Q1tab, const u16* __restrict__ W1s,
        const float* __restrict__ w2, const float* __restrict__ b2,
        float* __restrict__ out) {
    const int tid = threadIdx.x;
    const int b   = blockIdx.x;
    const int v   = tid;                         // 0..255, active if < VD
    const bool active = v < VD;
    const int vc = active ? v : VD - 1;

    float mv[MEMN];
    #pragma unroll
    for (int m = 0; m < MEMN; ++m) mv[m] = ivm[m * VD + vc];

    const int base = b * SS;
    int q_c = __builtin_amdgcn_readfirstlane(qd[base]);
    int q_n = __builtin_amdgcn_readfirstlane(qd[base + 1]);
    int qa0 = __builtin_amdgcn_readfirstlane(qad[base]);
    int qa1 = __builtin_amdgcn_readfirstlane(qad[base + 1]);
    u32 ea_c = EA[(size_t)qa0 * VD + vc];
    u32 ea_n = EA[(size_t)qa1 * VD + vc];

    for (int t = 0; t < SS; ++t) {
        int q_nn = 0, qa_nn = 0;
        if (t + 2 < SS) {
            q_nn  = __builtin_amdgcn_readfirstlane(qd[base + t + 2]);
            qa_nn = __builtin_amdgcn_readfirstlane(qad[base + t + 2]);
        }
        u32 ea_nn = EA[(size_t)qa_nn * VD + vc];

        const float* wrow = Wtab + q_c * MEMN;   // uniform -> s_load clause
        float ev = bfu16_to_f((u16)(ea_c & 0xffffu));
        float av = bfu16_to_f((u16)(ea_c >> 16));

        float rd0 = 0.f, rd1 = 0.f;
        #pragma unroll
        for (int m = 0; m < MEMN; m += 2) {      // 25 pairs, slots 0..49
            float wm0 = wrow[m], wm1 = wrow[m + 1];
            float m0 = mv[m], m1 = mv[m + 1];
            rd0 = fmaf(wm0, m0, rd0);
            mv[m]     = fmaf(wm0, fmaf(-ev, m0, av), m0);
            rd1 = fmaf(wm1, m1, rd1);
            mv[m + 1] = fmaf(wm1, fmaf(-ev, m1, av), m1);
        }
        if (active)
            READ[(size_t)(base + t) * VD + v] = f_to_bfu16(rd0 + rd1);
        q_c = q_n; q_n = q_nn; ea_c = ea_n; ea_n = ea_nn;
    }

    // ---- fused MLP tail: this block's 200 RD rows (L2-hot) ----
    __threadfence_block();
    __syncthreads();                              // all block RD writes drained

    const int lane = tid & 63;
    const int wv   = tid >> 6;
    const int mrow = lane & 15;        // A row within strip / C-D col (feature)
    const int quad = lane >> 4;
    const float b2f = b2[0];
    const u16* RDb = READ + (size_t)base * VD;

    for (int s = wv; s * 16 < SS; s += 4) {       // waves round-robin strips
        const int lrow0 = s * 16;
        // A fragments: clamp row to SS-1 (strip 12 rows 8..15 are garbage;
        // their outputs are guarded below — clamping keeps reads in-bounds)
        s8v a[7];
        {
            int ar = lrow0 + mrow; if (ar >= SS) ar = SS - 1;
            const u16* arow = RDb + (size_t)ar * VD + quad * 8;
            #pragma unroll
            for (int kt = 0; kt < 7; ++kt)
                a[kt] = *(const s8v*)(arow + kt * 32);   // k>=200 garbage * B=0
        }

        float pf[4] = {0.f, 0.f, 0.f, 0.f};
        #pragma unroll
        for (int nt = 0; nt < 4; ++nt) {
            s8v bfr[7];
            #pragma unroll
            for (int kt = 0; kt < 7; ++kt)
                bfr[kt] = *(const s8v*)(W1s + (((nt * 7 + kt) * 64) + lane) * 8);

            f4v acc = {0.f, 0.f, 0.f, 0.f};
            #pragma unroll
            for (int kt = 0; kt < 7; ++kt)
                acc = __builtin_amdgcn_mfma_f32_16x16x32_bf16(a[kt], bfr[kt], acc, 0, 0, 0);

            const int f = nt * 16 + mrow;                  // output feature col
            const float w2f = (f < FC) ? w2[f] : 0.f;
            #pragma unroll
            for (int r = 0; r < 4; ++r) {
                int lrow = lrow0 + quad * 4 + r;
                float q1v = (lrow < SS) ? Q1tab[qd[base + lrow] * FC + f] : 0.f;
                float h = acc[r] + q1v;
                pf[r] = fmaf(fast_tanh(h), w2f, pf[r]);
            }
        }

        #pragma unroll
        for (int r = 0; r < 4; ++r) {
            float sv = pf[r];
            sv += __shfl_xor(sv, 1, 64);
            sv += __shfl_xor(sv, 2, 64);
            sv += __shfl_xor(sv, 4, 64);
            sv += __shfl_xor(sv, 8, 64);
            int lrow = lrow0 + quad * 4 + r;
            if (mrow == 0 && lrow < SS)
                out[base + lrow] = fast_sigmoid(sv + b2f);
        }
    }
}

// ---- fallback (barrier version) if workspace too small ----
__global__ void dkvmn_main(const int* __restrict__ qd, const int* __restrict__ qad,
                           const float* __restrict__ Wtab, const float* __restrict__ Q1tab,
                           const u32* __restrict__ EA,
                           const float* __restrict__ ivm,
                           const float* __restrict__ w1,
                           const float* __restrict__ w2,
                           const float* __restrict__ b2,
                           float* __restrict__ out) {
    const int tid  = threadIdx.x;
    const int b    = blockIdx.x;
    const int v    = tid;
    const int lane = tid & 63;
    const int wv   = tid >> 6;

    __shared__ alignas(16) float read_lds[4 * 52];
    __shared__ alignas(16) float part_lds[4 * 52];

    float mv[MEMN];
    if (v < VD) {
        #pragma unroll
        for (int m = 0; m < MEMN; ++m) mv[m] = ivm[m * VD + v];
    }
    float w1r[50];
    if (lane < FC) {
        #pragma unroll
        for (int i = 0; i < 50; ++i) w1r[i] = w1[(wv * 50 + i) * FC + lane];
    } else {
        #pragma unroll
        for (int i = 0; i < 50; ++i) w1r[i] = 0.f;
    }
    const float w2f = (tid < FC) ? w2[tid] : 0.f;
    const float b2f = b2[0];

    const int* qrow_i  = qd  + b * SS;
    const int* qarow_i = qad + b * SS;
    const int jchunk = v / 50;
    const int wslot  = jchunk * 52 + (v - jchunk * 50);

    for (int t = 0; t < SS; ++t) {
        const int q  = __builtin_amdgcn_readfirstlane(qrow_i[t]);
        const int qa = __builtin_amdgcn_readfirstlane(qarow_i[t]);
        const float* wrow = Wtab + q * MEMN;

        u32 ea = 0;
        if (v < VD) ea = EA[(size_t)qa * VD + v];
        float ev = bfu16_to_f((u16)(ea & 0xffffu));
        float av = bfu16_to_f((u16)(ea >> 16));

        if (v < VD) {
            float rd0 = 0.f, rd1 = 0.f;
            #pragma unroll
            for (int m = 0; m < MEMN; m += 2) {
                float wm0 = wrow[m], wm1 = wrow[m + 1];
                rd0 = fmaf(wm0, mv[m], rd0);
                mv[m] = fmaf(wm0, fmaf(-ev, mv[m], av), mv[m]);
                rd1 = fmaf(wm1, mv[m + 1], rd1);
                mv[m + 1] = fmaf(wm1, fmaf(-ev, mv[m + 1], av), mv[m + 1]);
            }
            read_lds[wslot] = rd0 + rd1;
        }
        __syncthreads();

        float part = 0.f;
        {
            const float* rlc = read_lds + wv * 52;
            #pragma unroll
            for (int i = 0; i < 48; i += 4) {
                float4 x = *(const float4*)(rlc + i);
                part = fmaf(x.x, w1r[i],     part);
                part = fmaf(x.y, w1r[i + 1], part);
                part = fmaf(x.z, w1r[i + 2], part);
                part = fmaf(x.w, w1r[i + 3], part);
            }
            part = fmaf(rlc[48], w1r[48], part);
            part = fmaf(rlc[49], w1r[49], part);
        }
        if (lane < FC) part_lds[wv * 52 + lane] = part;
        __syncthreads();

        if (wv == 0) {
            float pf = 0.f;
            if (lane < FC) {
                float h = part_lds[lane] + part_lds[52 + lane] +
                          part_lds[104 + lane] + part_lds[156 + lane] +
                          Q1tab[q * FC + lane];
                pf = fast_tanh(h) * w2f;
            }
            #pragma unroll
            for (int off = 32; off >= 1; off >>= 1) pf += __shfl_xor(pf, off, 64);
            if (lane == 0) out[b * SS + t] = fast_sigmoid(pf + b2f);
        }
    }
}

extern "C" void kernel_launch(void* const* d_in, const int* in_sizes, int n_in,
                              void* d_out, int out_size, void* d_ws, size_t ws_size,
                              hipStream_t stream) {
    const int* qd  = (const int*)d_in[0];
    const int* qad = (const int*)d_in[1];
    const float* qemb  = (const float*)d_in[2];
    const float* qaemb = (const float*)d_in[3];
    const float* km    = (const float*)d_in[4];
    const float* ivm   = (const float*)d_in[5];
    const float* ew    = (const float*)d_in[6];
    const float* eb    = (const float*)d_in[7];
    const float* aw    = (const float*)d_in[8];
    const float* ab    = (const float*)d_in[9];
    const float* w1    = (const float*)d_in[10];
    const float* b1    = (const float*)d_in[11];
    const float* w2    = (const float*)d_in[12];
    const float* b2    = (const float*)d_in[13];
    float* out = (float*)d_out;
    (void)in_sizes; (void)n_in; (void)out_size;

    char* ws = (char*)d_ws;
    float* Wt  = (float*)(ws);                       // 1,000,200 -> pad 1,000,448
    float* Q1  = (float*)(ws + 1000448);             // 1,000,200 -> pad 1,000,448
    u32*   EA  = (u32*)  (ws + 2000896);             // 8,000,800 -> pad 8,001,024
    u16*   W1s = (u16*)  (ws + 10001920);            // 28,672    -> pad 32,768
    u16*   RD  = (u16*)  (ws + 10034688);            // 163,840,000 (+512 slack)
    const size_t need = 10034688ull + 163840000ull + 512ull;

    hipMemsetAsync(out + (size_t)BB * SS, 0, (size_t)3 * BB * SS * sizeof(float), stream);

    build_wq<<<NQ1, 64, 0, stream>>>(qemb, km, w1, b1, Wt, Q1);
    build_ea<<<(NQA + EA_R - 1) / EA_R, 256, 0, stream>>>(qaemb, ew, eb, aw, ab, EA);

    if (ws_size >= need) {
        pack_w1<<<56, 256, 0, stream>>>(w1, W1s);
        dkvmn_state<<<BB, 256, 0, stream>>>(qd, qad, Wt, EA, ivm, RD,
                                            Q1, W1s, w2, b2, out);
    } else {
        dkvmn_main<<<BB, 256, 0, stream>>>(qd, qad, Wt, Q1, EA, ivm, w1, w2, b2, out);
    }
}

// Round 11
// 492.796 us; speedup vs baseline: 1.6374x; 1.6374x over previous
//
#include <hip/hip_runtime.h>

// DKVMN forward, v11 — un-fuse (R10: tail pushed VGPR 32->100, occupancy
// 59->22%, state 356->719us) + 4-deep skewed EA prefetch in the state loop.
//  R10 lesson: fusion that inflates register demand taxes the whole kernel's
//  latency hiding. R9 structure restored (state VGPR 32, mlp separate).
//  State stall theory: depth-2 prefetch defeated by loop-carried phi copy
//  (wait lands 1 step after issue < gather latency). v11: manual x4 unroll,
//  ring of 4 in-flight EA gathers consumed 4 sub-steps after issue.
//  k1 build_wq : W[5001,50]=softmax(q_emb@K^T), Q1[5001,50]=q_emb@W1[200:250]+b1
//  k2 build_ea : EA[10001,200] packed bf16 {e,a} (f32 math, proven)
//  k2b pack_w1 : W1 -> bf16 MFMA B-frag order [4 nt][7 kt][64 lane][8]
//  k3 dkvmn_state: barrier-free recurrence, 256 thr, scalar fmaf, SGPR wrow,
//      4-deep skewed EA/q prefetch, writes RD bf16.
//  k4 mlp_pred : MFMA 16x16x32 bf16 GEMM [B*S,224]@[224,64] + fused epilogue.
// Workspace: Wt 1MB | Q1 1MB | EA 8MB | W1s 32KB | RD 164MB (~174MB total).

#define NQ1   5001
#define NQA   10001
#define MEMN  50
#define KD    50
#define VD    200
#define FC    50
#define BB    2048
#define SS    200
#define EA_R  16

typedef unsigned int   u32;
typedef unsigned short u16;
typedef short  s8v  __attribute__((ext_vector_type(8)));   // 8 bf16 (4 VGPRs)
typedef float  f4v  __attribute__((ext_vector_type(4)));   // MFMA C/D

__device__ __forceinline__ float fast_sigmoid(float x) { return 1.f / (1.f + __expf(-x)); }
__device__ __forceinline__ float fast_tanh(float x) {
    float e2 = __expf(2.f * x);           // inf-safe
    return 1.f - 2.f / (e2 + 1.f);
}
__device__ __forceinline__ float bfu16_to_f(u16 u) {
    union { float f; u32 i; } x; x.i = ((u32)u) << 16; return x.f;
}
__device__ __forceinline__ u16 f_to_bfu16(float f) {   // RNE, finite inputs
    union { float f; u32 i; } x; x.f = f;
    return (u16)((x.i + 0x7fffu + ((x.i >> 16) & 1u)) >> 16);
}

// ---- per-q tables ----
__global__ void build_wq(const float* __restrict__ qemb,
                         const float* __restrict__ km,
                         const float* __restrict__ w1,
                         const float* __restrict__ b1,
                         float* __restrict__ Wt, float* __restrict__ Q1) {
    const int q = blockIdx.x;
    const int f = threadIdx.x;          // one wave
    __shared__ float qrow[KD];
    if (f < KD) qrow[f] = qemb[q * KD + f];
    __syncthreads();

    float s = -1e30f;
    if (f < MEMN) {
        s = 0.f;
        #pragma unroll
        for (int k = 0; k < KD; ++k) s = fmaf(qrow[k], km[f * KD + k], s);
    }
    float mx = s;
    #pragma unroll
    for (int off = 32; off >= 1; off >>= 1) mx = fmaxf(mx, __shfl_xor(mx, off, 64));
    float e = (f < MEMN) ? __expf(s - mx) : 0.f;
    float sum = e;
    #pragma unroll
    for (int off = 32; off >= 1; off >>= 1) sum += __shfl_xor(sum, off, 64);
    if (f < MEMN) Wt[q * MEMN + f] = e / sum;

    if (f < FC) {
        float h = b1[f];
        #pragma unroll
        for (int k = 0; k < KD; ++k)
            h = fmaf(qrow[k], w1[(VD + k) * FC + f], h);
        Q1[q * FC + f] = h;
    }
}

// ---- per-qa table, packed {e,a} bf16 (f32 math — protocol-proven) ----
__global__ void build_ea(const float* __restrict__ qaemb,
                         const float* __restrict__ ew,
                         const float* __restrict__ ebias,
                         const float* __restrict__ aw,
                         const float* __restrict__ abias,
                         u32* __restrict__ EA) {
    __shared__ float qT[VD][EA_R];
    const int tid = threadIdx.x;
    const int r0 = blockIdx.x * EA_R;
    if (tid < VD) {
        #pragma unroll
        for (int r = 0; r < EA_R; ++r) {
            int row = r0 + r;
            qT[tid][r] = (row < NQA) ? qaemb[(size_t)row * VD + tid] : 0.f;
        }
    }
    __syncthreads();
    if (tid >= VD) return;

    float accE[EA_R], accA[EA_R];
    #pragma unroll
    for (int r = 0; r < EA_R; ++r) { accE[r] = 0.f; accA[r] = 0.f; }
    for (int k = 0; k < VD; ++k) {
        float we = ew[k * VD + tid];
        float wa = aw[k * VD + tid];
        #pragma unroll
        for (int r = 0; r < EA_R; ++r) {
            float qv = qT[k][r];
            accE[r] = fmaf(qv, we, accE[r]);
            accA[r] = fmaf(qv, wa, accA[r]);
        }
    }
    float be = ebias[tid], ba = abias[tid];
    #pragma unroll
    for (int r = 0; r < EA_R; ++r) {
        int row = r0 + r;
        if (row < NQA) {
            u16 e16 = f_to_bfu16(fast_sigmoid(accE[r] + be));
            u16 a16 = f_to_bfu16(fast_tanh(accA[r] + ba));
            EA[(size_t)row * VD + tid] = (u32)e16 | ((u32)a16 << 16);
        }
    }
}

// ---- W1 -> bf16 MFMA B-fragment order: idx = ((nt*7+kt)*64+lane)*8+j,
//      element = w1[k = kt*32+(lane>>4)*8+j][n = nt*16+(lane&15)], 0-padded ----
__global__ void pack_w1(const float* __restrict__ w1, u16* __restrict__ W1s) {
    for (int idx = blockIdx.x * blockDim.x + threadIdx.x; idx < 4 * 7 * 64 * 8;
         idx += gridDim.x * blockDim.x) {
        int j    = idx & 7;
        int lane = (idx >> 3) & 63;
        int kt   = (idx >> 9) % 7;
        int nt   = idx / 3584;
        int k = kt * 32 + ((lane >> 4) << 3) + j;
        int n = nt * 16 + (lane & 15);
        float v = (k < VD && n < FC) ? w1[k * FC + n] : 0.f;
        W1s[idx] = f_to_bfu16(v);
    }
}

// ---- recurrence: 256 thr, scalar fmaf, SGPR wrow, 4-deep skewed prefetch ----
__global__ __launch_bounds__(256) void dkvmn_state(
        const int* __restrict__ qd, const int* __restrict__ qad,
        const float* __restrict__ Wtab, const u32* __restrict__ EA,
        const float* __restrict__ ivm, u16* __restrict__ READ) {
    const int tid = threadIdx.x;
    const int b   = blockIdx.x;
    const int v   = tid;                         // 0..255, active if < VD
    const bool active = v < VD;
    const int vc = active ? v : VD - 1;

    float mv[MEMN];
    #pragma unroll
    for (int m = 0; m < MEMN; ++m) mv[m] = ivm[m * VD + vc];

    const int base = b * SS;

    // 4-deep ring: eabuf[u]/qbuf[u] hold values for step t (t%4==u)
    u32 eabuf[4];
    int qbuf[4];
    #pragma unroll
    for (int d = 0; d < 4; ++d) {
        qbuf[d] = __builtin_amdgcn_readfirstlane(qd[base + d]);
        int qa  = __builtin_amdgcn_readfirstlane(qad[base + d]);
        eabuf[d] = EA[(size_t)qa * VD + vc];
    }

    for (int t = 0; t < SS; t += 4) {
        #pragma unroll
        for (int u = 0; u < 4; ++u) {
            const int tc = t + u;
            // prefetch step tc+4 (clamped; dup loads past the end are unused)
            int tn = tc + 4; tn = (tn < SS) ? tn : (SS - 1);
            int q_p  = __builtin_amdgcn_readfirstlane(qd[base + tn]);
            int qa_p = __builtin_amdgcn_readfirstlane(qad[base + tn]);
            u32 ea_p = EA[(size_t)qa_p * VD + vc];

            const float* wrow = Wtab + qbuf[u] * MEMN;   // uniform -> s_load
            const u32 ea_c = eabuf[u];
            float ev = bfu16_to_f((u16)(ea_c & 0xffffu));
            float av = bfu16_to_f((u16)(ea_c >> 16));

            float rd0 = 0.f, rd1 = 0.f;
            #pragma unroll
            for (int m = 0; m < MEMN; m += 2) {          // 25 pairs, slots 0..49
                float wm0 = wrow[m], wm1 = wrow[m + 1];
                float m0 = mv[m], m1 = mv[m + 1];
                rd0 = fmaf(wm0, m0, rd0);
                mv[m]     = fmaf(wm0, fmaf(-ev, m0, av), m0);
                rd1 = fmaf(wm1, m1, rd1);
                mv[m + 1] = fmaf(wm1, fmaf(-ev, m1, av), m1);
            }
            if (active)
                READ[(size_t)(base + tc) * VD + v] = f_to_bfu16(rd0 + rd1);
            qbuf[u] = q_p; eabuf[u] = ea_p;
        }
    }
}

// ---- prediction MLP via MFMA: per wave one 16-row strip, K=224, N=64 ----
__global__ __launch_bounds__(256) void mlp_pred(
        const u16* __restrict__ RD, const int* __restrict__ qd,
        const float* __restrict__ Q1tab, const u16* __restrict__ W1s,
        const float* __restrict__ w2, const float* __restrict__ b2,
        float* __restrict__ out) {
    const int tid  = threadIdx.x;
    const int lane = tid & 63;
    const int wv   = tid >> 6;
    const int strip = blockIdx.x * 4 + wv;
    const int row0  = strip * 16;

    const int mrow = lane & 15;        // A row within strip / C-D col (feature)
    const int quad = lane >> 4;

    s8v a[7];
    {
        const u16* arow = RD + (size_t)(row0 + mrow) * VD + quad * 8;
        #pragma unroll
        for (int kt = 0; kt < 7; ++kt)
            a[kt] = *(const s8v*)(arow + kt * 32);   // k>=200 garbage * B=0
    }

    const float b2f = b2[0];
    float pf[4] = {0.f, 0.f, 0.f, 0.f};

    #pragma unroll
    for (int nt = 0; nt < 4; ++nt) {
        s8v bfr[7];
        #pragma unroll
        for (int kt = 0; kt < 7; ++kt)
            bfr[kt] = *(const s8v*)(W1s + (((nt * 7 + kt) * 64) + lane) * 8);

        f4v acc = {0.f, 0.f, 0.f, 0.f};
        #pragma unroll
        for (int kt = 0; kt < 7; ++kt)
            acc = __builtin_amdgcn_mfma_f32_16x16x32_bf16(a[kt], bfr[kt], acc, 0, 0, 0);

        const int f = nt * 16 + mrow;                  // output feature col
        const float w2f = (f < FC) ? w2[f] : 0.f;
        #pragma unroll
        for (int r = 0; r < 4; ++r) {
            int row = row0 + quad * 4 + r;
            float h = acc[r] + Q1tab[qd[row] * FC + f];
            pf[r] = fmaf(fast_tanh(h), w2f, pf[r]);
        }
    }

    #pragma unroll
    for (int r = 0; r < 4; ++r) {
        float s = pf[r];
        s += __shfl_xor(s, 1, 64);
        s += __shfl_xor(s, 2, 64);
        s += __shfl_xor(s, 4, 64);
        s += __shfl_xor(s, 8, 64);
        if (mrow == 0)
            out[row0 + quad * 4 + r] = fast_sigmoid(s + b2f);
    }
}

// ---- fallback (barrier version) if workspace too small ----
__global__ void dkvmn_main(const int* __restrict__ qd, const int* __restrict__ qad,
                           const float* __restrict__ Wtab, const float* __restrict__ Q1tab,
                           const u32* __restrict__ EA,
                           const float* __restrict__ ivm,
                           const float* __restrict__ w1,
                           const float* __restrict__ w2,
                           const float* __restrict__ b2,
                           float* __restrict__ out) {
    const int tid  = threadIdx.x;
    const int b    = blockIdx.x;
    const int v    = tid;
    const int lane = tid & 63;
    const int wv   = tid >> 6;

    __shared__ alignas(16) float read_lds[4 * 52];
    __shared__ alignas(16) float part_lds[4 * 52];

    float mv[MEMN];
    if (v < VD) {
        #pragma unroll
        for (int m = 0; m < MEMN; ++m) mv[m] = ivm[m * VD + v];
    }
    float w1r[50];
    if (lane < FC) {
        #pragma unroll
        for (int i = 0; i < 50; ++i) w1r[i] = w1[(wv * 50 + i) * FC + lane];
    } else {
        #pragma unroll
        for (int i = 0; i < 50; ++i) w1r[i] = 0.f;
    }
    const float w2f = (tid < FC) ? w2[tid] : 0.f;
    const float b2f = b2[0];

    const int* qrow_i  = qd  + b * SS;
    const int* qarow_i = qad + b * SS;
    const int jchunk = v / 50;
    const int wslot  = jchunk * 52 + (v - jchunk * 50);

    for (int t = 0; t < SS; ++t) {
        const int q  = __builtin_amdgcn_readfirstlane(qrow_i[t]);
        const int qa = __builtin_amdgcn_readfirstlane(qarow_i[t]);
        const float* wrow = Wtab + q * MEMN;

        u32 ea = 0;
        if (v < VD) ea = EA[(size_t)qa * VD + v];
        float ev = bfu16_to_f((u16)(ea & 0xffffu));
        float av = bfu16_to_f((u16)(ea >> 16));

        if (v < VD) {
            float rd0 = 0.f, rd1 = 0.f;
            #pragma unroll
            for (int m = 0; m < MEMN; m += 2) {
                float wm0 = wrow[m], wm1 = wrow[m + 1];
                rd0 = fmaf(wm0, mv[m], rd0);
                mv[m] = fmaf(wm0, fmaf(-ev, mv[m], av), mv[m]);
                rd1 = fmaf(wm1, mv[m + 1], rd1);
                mv[m + 1] = fmaf(wm1, fmaf(-ev, mv[m + 1], av), mv[m + 1]);
            }
            read_lds[wslot] = rd0 + rd1;
        }
        __syncthreads();

        float part = 0.f;
        {
            const float* rlc = read_lds + wv * 52;
            #pragma unroll
            for (int i = 0; i < 48; i += 4) {
                float4 x = *(const float4*)(rlc + i);
                part = fmaf(x.x, w1r[i],     part);
                part = fmaf(x.y, w1r[i + 1], part);
                part = fmaf(x.z, w1r[i + 2], part);
                part = fmaf(x.w, w1r[i + 3], part);
            }
            part = fmaf(rlc[48], w1r[48], part);
            part = fmaf(rlc[49], w1r[49], part);
        }
        if (lane < FC) part_lds[wv * 52 + lane] = part;
        __syncthreads();

        if (wv == 0) {
            float pf = 0.f;
            if (lane < FC) {
                float h = part_lds[lane] + part_lds[52 + lane] +
                          part_lds[104 + lane] + part_lds[156 + lane] +
                          Q1tab[q * FC + lane];
                pf = fast_tanh(h) * w2f;
            }
            #pragma unroll
            for (int off = 32; off >= 1; off >>= 1) pf += __shfl_xor(pf, off, 64);
            if (lane == 0) out[b * SS + t] = fast_sigmoid(pf + b2f);
        }
    }
}

extern "C" void kernel_launch(void* const* d_in, const int* in_sizes, int n_in,
                              void* d_out, int out_size, void* d_ws, size_t ws_size,
                              hipStream_t stream) {
    const int* qd  = (const int*)d_in[0];
    const int* qad = (const int*)d_in[1];
    const float* qemb  = (const float*)d_in[2];
    const float* qaemb = (const float*)d_in[3];
    const float* km    = (const float*)d_in[4];
    const float* ivm   = (const float*)d_in[5];
    const float* ew    = (const float*)d_in[6];
    const float* eb    = (const float*)d_in[7];
    const float* aw    = (const float*)d_in[8];
    const float* ab    = (const float*)d_in[9];
    const float* w1    = (const float*)d_in[10];
    const float* b1    = (const float*)d_in[11];
    const float* w2    = (const float*)d_in[12];
    const float* b2    = (const float*)d_in[13];
    float* out = (float*)d_out;
    (void)in_sizes; (void)n_in; (void)out_size;

    char* ws = (char*)d_ws;
    float* Wt  = (float*)(ws);                       // 1,000,200 -> pad 1,000,448
    float* Q1  = (float*)(ws + 1000448);             // 1,000,200 -> pad 1,000,448
    u32*   EA  = (u32*)  (ws + 2000896);             // 8,000,800 -> pad 8,001,024
    u16*   W1s = (u16*)  (ws + 10001920);            // 28,672    -> pad 32,768
    u16*   RD  = (u16*)  (ws + 10034688);            // 163,840,000 (+512 slack)
    const size_t need = 10034688ull + 163840000ull + 512ull;

    hipMemsetAsync(out + (size_t)BB * SS, 0, (size_t)3 * BB * SS * sizeof(float), stream);

    build_wq<<<NQ1, 64, 0, stream>>>(qemb, km, w1, b1, Wt, Q1);
    build_ea<<<(NQA + EA_R - 1) / EA_R, 256, 0, stream>>>(qaemb, ew, eb, aw, ab, EA);

    if (ws_size >= need) {
        pack_w1<<<56, 256, 0, stream>>>(w1, W1s);
        dkvmn_state<<<BB, 256, 0, stream>>>(qd, qad, Wt, EA, ivm, RD);
        mlp_pred<<<(BB * SS) / 64, 256, 0, stream>>>(RD, qd, Q1, W1s, w2, b2, out);
    } else {
        dkvmn_main<<<BB, 256, 0, stream>>>(qd, qad, Wt, Q1, EA, ivm, w1, w2, b2, out);
    }
}

// Round 12
// 482.332 us; speedup vs baseline: 1.6729x; 1.0217x over previous
//
#include <hip/hip_runtime.h>
#include <hip/hip_fp16.h>

// DKVMN forward, v12 — f16-packed state math (the 2x issue lever).
//  R6/R9/R11 established: state is pinned at the f32 VALU-issue floor
//  (~370cyc/step); pk-f32 is rate-neutral (fp32 peak == scalar rate); prefetch
//  depth and LDS staging don't move it. v_pk_fma_f16 is true 2x: Mv as 25
//  half2 pairs, w as f16-pair table (SGPR-loadable), e/a broadcast half2 ->
//  75 pk-FMAs/step instead of 150 scalar.
//  Precision: e/a already bf16 (eps 8e-3, passes at 0.0039); f16 adds ~2e-3.
//  k1 build_wq : Wt f32 row + Wh f16-pair row + Q1
//  k2 build_ea : EA[10001,200] packed bf16 {e,a} (f32 math, proven)
//  k2b pack_w1 : W1 -> bf16 MFMA B-frag order
//  k3 dkvmn_state: barrier-free recurrence, 256 thr, pk-f16, SGPR wrow pairs,
//      EA prefetch depth 2, writes RD bf16.
//  k4 mlp_pred : MFMA 16x16x32 bf16 GEMM [B*S,224]@[224,64] + fused epilogue.
// Workspace: Wt 1MB | Q1 1MB | EA 8MB | W1s 32KB | Wh 0.6MB | RD 164MB.

#define NQ1   5001
#define NQA   10001
#define MEMN  50
#define KD    50
#define VD    200
#define FC    50
#define BB    2048
#define SS    200
#define EA_R  16
#define WHS   28       // Wh row stride in u32 (25 pairs + 3 pad, 112B)

typedef unsigned int   u32;
typedef unsigned short u16;
typedef short  s8v  __attribute__((ext_vector_type(8)));   // 8 bf16 (4 VGPRs)
typedef float  f4v  __attribute__((ext_vector_type(4)));   // MFMA C/D

__device__ __forceinline__ float fast_sigmoid(float x) { return 1.f / (1.f + __expf(-x)); }
__device__ __forceinline__ float fast_tanh(float x) {
    float e2 = __expf(2.f * x);           // inf-safe
    return 1.f - 2.f / (e2 + 1.f);
}
__device__ __forceinline__ float bfu16_to_f(u16 u) {
    union { float f; u32 i; } x; x.i = ((u32)u) << 16; return x.f;
}
__device__ __forceinline__ u16 f_to_bfu16(float f) {   // RNE, finite inputs
    union { float f; u32 i; } x; x.f = f;
    return (u16)((x.i + 0x7fffu + ((x.i >> 16) & 1u)) >> 16);
}
__device__ __forceinline__ __half2 u32_to_h2(u32 u) {
    union { u32 i; __half2 h; } x; x.i = u; return x.h;
}

// ---- per-q tables: softmax row (f32 + f16-pair), q-half of MLP layer 1 ----
__global__ void build_wq(const float* __restrict__ qemb,
                         const float* __restrict__ km,
                         const float* __restrict__ w1,
                         const float* __restrict__ b1,
                         float* __restrict__ Wt, u32* __restrict__ Wh,
                         float* __restrict__ Q1) {
    const int q = blockIdx.x;
    const int f = threadIdx.x;          // one wave
    __shared__ float qrow[KD];
    if (f < KD) qrow[f] = qemb[q * KD + f];
    __syncthreads();

    float s = -1e30f;
    if (f < MEMN) {
        s = 0.f;
        #pragma unroll
        for (int k = 0; k < KD; ++k) s = fmaf(qrow[k], km[f * KD + k], s);
    }
    float mx = s;
    #pragma unroll
    for (int off = 32; off >= 1; off >>= 1) mx = fmaxf(mx, __shfl_xor(mx, off, 64));
    float e = (f < MEMN) ? __expf(s - mx) : 0.f;
    float sum = e;
    #pragma unroll
    for (int off = 32; off >= 1; off >>= 1) sum += __shfl_xor(sum, off, 64);
    float wv_ = (f < MEMN) ? (e / sum) : 0.f;
    if (f < MEMN) Wt[q * MEMN + f] = wv_;

    // f16-pair row: lane i<25 packs (w[2i], w[2i+1])
    float plo = __shfl(wv_, 2 * (f & 31), 64);
    float phi = __shfl(wv_, 2 * (f & 31) + 1, 64);
    if (f < 25) {
        union { __half h; u16 u; } lo, hi;
        lo.h = __float2half(plo); hi.h = __float2half(phi);
        Wh[q * WHS + f] = (u32)lo.u | ((u32)hi.u << 16);
    } else if (f < WHS) {
        Wh[q * WHS + f] = 0;
    }

    if (f < FC) {
        float h = b1[f];
        #pragma unroll
        for (int k = 0; k < KD; ++k)
            h = fmaf(qrow[k], w1[(VD + k) * FC + f], h);
        Q1[q * FC + f] = h;
    }
}

// ---- per-qa table, packed {e,a} bf16 (f32 math — protocol-proven) ----
__global__ void build_ea(const float* __restrict__ qaemb,
                         const float* __restrict__ ew,
                         const float* __restrict__ ebias,
                         const float* __restrict__ aw,
                         const float* __restrict__ abias,
                         u32* __restrict__ EA) {
    __shared__ float qT[VD][EA_R];
    const int tid = threadIdx.x;
    const int r0 = blockIdx.x * EA_R;
    if (tid < VD) {
        #pragma unroll
        for (int r = 0; r < EA_R; ++r) {
            int row = r0 + r;
            qT[tid][r] = (row < NQA) ? qaemb[(size_t)row * VD + tid] : 0.f;
        }
    }
    __syncthreads();
    if (tid >= VD) return;

    float accE[EA_R], accA[EA_R];
    #pragma unroll
    for (int r = 0; r < EA_R; ++r) { accE[r] = 0.f; accA[r] = 0.f; }
    for (int k = 0; k < VD; ++k) {
        float we = ew[k * VD + tid];
        float wa = aw[k * VD + tid];
        #pragma unroll
        for (int r = 0; r < EA_R; ++r) {
            float qv = qT[k][r];
            accE[r] = fmaf(qv, we, accE[r]);
            accA[r] = fmaf(qv, wa, accA[r]);
        }
    }
    float be = ebias[tid], ba = abias[tid];
    #pragma unroll
    for (int r = 0; r < EA_R; ++r) {
        int row = r0 + r;
        if (row < NQA) {
            u16 e16 = f_to_bfu16(fast_sigmoid(accE[r] + be));
            u16 a16 = f_to_bfu16(fast_tanh(accA[r] + ba));
            EA[(size_t)row * VD + tid] = (u32)e16 | ((u32)a16 << 16);
        }
    }
}

// ---- W1 -> bf16 MFMA B-fragment order ----
__global__ void pack_w1(const float* __restrict__ w1, u16* __restrict__ W1s) {
    for (int idx = blockIdx.x * blockDim.x + threadIdx.x; idx < 4 * 7 * 64 * 8;
         idx += gridDim.x * blockDim.x) {
        int j    = idx & 7;
        int lane = (idx >> 3) & 63;
        int kt   = (idx >> 9) % 7;
        int nt   = idx / 3584;
        int k = kt * 32 + ((lane >> 4) << 3) + j;
        int n = nt * 16 + (lane & 15);
        float v = (k < VD && n < FC) ? w1[k * FC + n] : 0.f;
        W1s[idx] = f_to_bfu16(v);
    }
}

// ---- recurrence: 256 thr, packed-f16 math, SGPR w pairs, EA depth-2 ----
__global__ __launch_bounds__(256) void dkvmn_state(
        const int* __restrict__ qd, const int* __restrict__ qad,
        const u32* __restrict__ Wh, const u32* __restrict__ EA,
        const float* __restrict__ ivm, u16* __restrict__ READ) {
    const int tid = threadIdx.x;
    const int b   = blockIdx.x;
    const int v   = tid;                         // 0..255, active if < VD
    const bool active = v < VD;
    const int vc = active ? v : VD - 1;

    __half2 mv[25];                              // pair i = slots (2i, 2i+1)
    #pragma unroll
    for (int i = 0; i < 25; ++i)
        mv[i] = __floats2half2_rn(ivm[(2 * i) * VD + vc],
                                  ivm[(2 * i + 1) * VD + vc]);

    const int base = b * SS;
    int q_c = __builtin_amdgcn_readfirstlane(qd[base]);
    int q_n = __builtin_amdgcn_readfirstlane(qd[base + 1]);
    int qa0 = __builtin_amdgcn_readfirstlane(qad[base]);
    int qa1 = __builtin_amdgcn_readfirstlane(qad[base + 1]);
    u32 ea_c = EA[(size_t)qa0 * VD + vc];
    u32 ea_n = EA[(size_t)qa1 * VD + vc];

    for (int t = 0; t < SS; ++t) {
        // prefetch step t+2 (clamped index; duplicate load harmless)
        int tn = t + 2; tn = (tn < SS) ? tn : (SS - 1);
        int q_nn  = __builtin_amdgcn_readfirstlane(qd[base + tn]);
        int qa_nn = __builtin_amdgcn_readfirstlane(qad[base + tn]);
        u32 ea_nn = EA[(size_t)qa_nn * VD + vc];

        const u32* wrow = Wh + q_c * WHS;        // uniform -> s_load clause
        float ev = bfu16_to_f((u16)(ea_c & 0xffffu));
        float av = bfu16_to_f((u16)(ea_c >> 16));
        __half2 av2 = __float2half2_rn(av);
        __half2 nev2 = __float2half2_rn(-ev);

        __half2 rdA = __float2half2_rn(0.f), rdB = __float2half2_rn(0.f);
        #pragma unroll
        for (int i = 0; i < 25; i += 2) {        // 13 iters (i=24 single)
            __half2 w0 = u32_to_h2(wrow[i]);
            rdA = __hfma2(w0, mv[i], rdA);
            mv[i] = __hfma2(w0, __hfma2(nev2, mv[i], av2), mv[i]);
            if (i + 1 < 25) {
                __half2 w1p = u32_to_h2(wrow[i + 1]);
                rdB = __hfma2(w1p, mv[i + 1], rdB);
                mv[i + 1] = __hfma2(w1p, __hfma2(nev2, mv[i + 1], av2), mv[i + 1]);
            }
        }
        if (active) {
            __half2 s2 = __hadd2(rdA, rdB);
            float rd = __half2float(__low2half(s2)) + __half2float(__high2half(s2));
            READ[(size_t)(base + t) * VD + v] = f_to_bfu16(rd);
        }
        q_c = q_n; q_n = q_nn; ea_c = ea_n; ea_n = ea_nn;
    }
}

// ---- prediction MLP via MFMA: per wave one 16-row strip, K=224, N=64 ----
__global__ __launch_bounds__(256) void mlp_pred(
        const u16* __restrict__ RD, const int* __restrict__ qd,
        const float* __restrict__ Q1tab, const u16* __restrict__ W1s,
        const float* __restrict__ w2, const float* __restrict__ b2,
        float* __restrict__ out) {
    const int tid  = threadIdx.x;
    const int lane = tid & 63;
    const int wv   = tid >> 6;
    const int strip = blockIdx.x * 4 + wv;
    const int row0  = strip * 16;

    const int mrow = lane & 15;        // A row within strip / C-D col (feature)
    const int quad = lane >> 4;

    s8v a[7];
    {
        const u16* arow = RD + (size_t)(row0 + mrow) * VD + quad * 8;
        #pragma unroll
        for (int kt = 0; kt < 7; ++kt)
            a[kt] = *(const s8v*)(arow + kt * 32);   // k>=200 garbage * B=0
    }

    const float b2f = b2[0];
    float pf[4] = {0.f, 0.f, 0.f, 0.f};

    #pragma unroll
    for (int nt = 0; nt < 4; ++nt) {
        s8v bfr[7];
        #pragma unroll
        for (int kt = 0; kt < 7; ++kt)
            bfr[kt] = *(const s8v*)(W1s + (((nt * 7 + kt) * 64) + lane) * 8);

        f4v acc = {0.f, 0.f, 0.f, 0.f};
        #pragma unroll
        for (int kt = 0; kt < 7; ++kt)
            acc = __builtin_amdgcn_mfma_f32_16x16x32_bf16(a[kt], bfr[kt], acc, 0, 0, 0);

        const int f = nt * 16 + mrow;                  // output feature col
        const float w2f = (f < FC) ? w2[f] : 0.f;
        #pragma unroll
        for (int r = 0; r < 4; ++r) {
            int row = row0 + quad * 4 + r;
            float h = acc[r] + Q1tab[qd[row] * FC + f];
            pf[r] = fmaf(fast_tanh(h), w2f, pf[r]);
        }
    }

    #pragma unroll
    for (int r = 0; r < 4; ++r) {
        float s = pf[r];
        s += __shfl_xor(s, 1, 64);
        s += __shfl_xor(s, 2, 64);
        s += __shfl_xor(s, 4, 64);
        s += __shfl_xor(s, 8, 64);
        if (mrow == 0)
            out[row0 + quad * 4 + r] = fast_sigmoid(s + b2f);
    }
}

// ---- fallback (barrier version, f32) if workspace too small ----
__global__ void dkvmn_main(const int* __restrict__ qd, const int* __restrict__ qad,
                           const float* __restrict__ Wtab, const float* __restrict__ Q1tab,
                           const u32* __restrict__ EA,
                           const float* __restrict__ ivm,
                           const float* __restrict__ w1,
                           const float* __restrict__ w2,
                           const float* __restrict__ b2,
                           float* __restrict__ out) {
    const int tid  = threadIdx.x;
    const int b    = blockIdx.x;
    const int v    = tid;
    const int lane = tid & 63;
    const int wv   = tid >> 6;

    __shared__ alignas(16) float read_lds[4 * 52];
    __shared__ alignas(16) float part_lds[4 * 52];

    float mv[MEMN];
    if (v < VD) {
        #pragma unroll
        for (int m = 0; m < MEMN; ++m) mv[m] = ivm[m * VD + v];
    }
    float w1r[50];
    if (lane < FC) {
        #pragma unroll
        for (int i = 0; i < 50; ++i) w1r[i] = w1[(wv * 50 + i) * FC + lane];
    } else {
        #pragma unroll
        for (int i = 0; i < 50; ++i) w1r[i] = 0.f;
    }
    const float w2f = (tid < FC) ? w2[tid] : 0.f;
    const float b2f = b2[0];

    const int* qrow_i  = qd  + b * SS;
    const int* qarow_i = qad + b * SS;
    const int jchunk = v / 50;
    const int wslot  = jchunk * 52 + (v - jchunk * 50);

    for (int t = 0; t < SS; ++t) {
        const int q  = __builtin_amdgcn_readfirstlane(qrow_i[t]);
        const int qa = __builtin_amdgcn_readfirstlane(qarow_i[t]);
        const float* wrow = Wtab + q * MEMN;

        u32 ea = 0;
        if (v < VD) ea = EA[(size_t)qa * VD + v];
        float ev = bfu16_to_f((u16)(ea & 0xffffu));
        float av = bfu16_to_f((u16)(ea >> 16));

        if (v < VD) {
            float rd0 = 0.f, rd1 = 0.f;
            #pragma unroll
            for (int m = 0; m < MEMN; m += 2) {
                float wm0 = wrow[m], wm1 = wrow[m + 1];
                rd0 = fmaf(wm0, mv[m], rd0);
                mv[m] = fmaf(wm0, fmaf(-ev, mv[m], av), mv[m]);
                rd1 = fmaf(wm1, mv[m + 1], rd1);
                mv[m + 1] = fmaf(wm1, fmaf(-ev, mv[m + 1], av), mv[m + 1]);
            }
            read_lds[wslot] = rd0 + rd1;
        }
        __syncthreads();

        float part = 0.f;
        {
            const float* rlc = read_lds + wv * 52;
            #pragma unroll
            for (int i = 0; i < 48; i += 4) {
                float4 x = *(const float4*)(rlc + i);
                part = fmaf(x.x, w1r[i],     part);
                part = fmaf(x.y, w1r[i + 1], part);
                part = fmaf(x.z, w1r[i + 2], part);
                part = fmaf(x.w, w1r[i + 3], part);
            }
            part = fmaf(rlc[48], w1r[48], part);
            part = fmaf(rlc[49], w1r[49], part);
        }
        if (lane < FC) part_lds[wv * 52 + lane] = part;
        __syncthreads();

        if (wv == 0) {
            float pf = 0.f;
            if (lane < FC) {
                float h = part_lds[lane] + part_lds[52 + lane] +
                          part_lds[104 + lane] + part_lds[156 + lane] +
                          Q1tab[q * FC + lane];
                pf = fast_tanh(h) * w2f;
            }
            #pragma unroll
            for (int off = 32; off >= 1; off >>= 1) pf += __shfl_xor(pf, off, 64);
            if (lane == 0) out[b * SS + t] = fast_sigmoid(pf + b2f);
        }
    }
}

extern "C" void kernel_launch(void* const* d_in, const int* in_sizes, int n_in,
                              void* d_out, int out_size, void* d_ws, size_t ws_size,
                              hipStream_t stream) {
    const int* qd  = (const int*)d_in[0];
    const int* qad = (const int*)d_in[1];
    const float* qemb  = (const float*)d_in[2];
    const float* qaemb = (const float*)d_in[3];
    const float* km    = (const float*)d_in[4];
    const float* ivm   = (const float*)d_in[5];
    const float* ew    = (const float*)d_in[6];
    const float* eb    = (const float*)d_in[7];
    const float* aw    = (const float*)d_in[8];
    const float* ab    = (const float*)d_in[9];
    const float* w1    = (const float*)d_in[10];
    const float* b1    = (const float*)d_in[11];
    const float* w2    = (const float*)d_in[12];
    const float* b2    = (const float*)d_in[13];
    float* out = (float*)d_out;
    (void)in_sizes; (void)n_in; (void)out_size;

    char* ws = (char*)d_ws;
    float* Wt  = (float*)(ws);                       // 1,000,200 -> pad 1,000,448
    float* Q1  = (float*)(ws + 1000448);             // 1,000,200 -> pad 1,000,448
    u32*   EA  = (u32*)  (ws + 2000896);             // 8,000,800 -> pad 8,001,024
    u16*   W1s = (u16*)  (ws + 10001920);            // 28,672    -> pad 32,768
    u32*   Wh  = (u32*)  (ws + 10034688);            // 5001*28*4=560,112 -> pad 560,640
    u16*   RD  = (u16*)  (ws + 10595328);            // 163,840,000
    const size_t need = 10595328ull + 163840000ull + 512ull;

    hipMemsetAsync(out + (size_t)BB * SS, 0, (size_t)3 * BB * SS * sizeof(float), stream);

    build_wq<<<NQ1, 64, 0, stream>>>(qemb, km, w1, b1, Wt, Wh, Q1);
    build_ea<<<(NQA + EA_R - 1) / EA_R, 256, 0, stream>>>(qaemb, ew, eb, aw, ab, EA);

    if (ws_size >= need) {
        pack_w1<<<56, 256, 0, stream>>>(w1, W1s);
        dkvmn_state<<<BB, 256, 0, stream>>>(qd, qad, Wh, EA, ivm, RD);
        mlp_pred<<<(BB * SS) / 64, 256, 0, stream>>>(RD, qd, Q1, W1s, w2, b2, out);
    } else {
        dkvmn_main<<<BB, 256, 0, stream>>>(qd, qad, Wt, Q1, EA, ivm, w1, w2, b2, out);
    }
}